// Round 9
// baseline (527.923 us; speedup 1.0000x reference)
//
#include <hip/hip_runtime.h>
#include <hip/hip_bf16.h>
#include <math.h>

#define N_NODES 50000
#define N_EDGES 800000
#define D 64
#define ED 32

// ws layout (float-slot offsets). Total ~20.95M slots = 83.8 MB.
#define Q_OFF    0          // bf16 q (1.6M slots)
#define K_OFF    1600000    // bf16 k
#define V_OFF    3200000    // bf16 v
#define EE_OFF   4800000    // fp8 ee, dst-sorted: 800k x 64 B = 12.8M slots
#define OS_OFF   17600000   // bf16 osum: 1.6M slots
#define S_OFF    19200000   // 16
#define RP_OFF   19200016   // 50,001 (+1 pad)
#define SRCP_OFF 19250018   // 800k ints
#define EIDP_OFF 20050018   // 800k ints
#define DEG_OFF  20850018   // 50k ints
#define WOFF_OFF 20900018   // 50k ints
// aliases (dead ranges reused):
#define H_OFF    0          // h f32 3.2M over q/k/v (dead after gather)
#define F1_OFF   EE_OFF     // f1 f32 6.4M over ee (dead after gather)

typedef __bf16 bf16x8 __attribute__((ext_vector_type(8)));
typedef float  f32x4  __attribute__((ext_vector_type(4)));

__device__ __forceinline__ ushort f2bf(float f) {
  uint u = __float_as_uint(f);
  uint r = (u + 0x7FFFu + ((u >> 16) & 1u)) >> 16;
  return (ushort)r;
}
__device__ __forceinline__ float rlane(float v, int l) {
  return __uint_as_float(__builtin_amdgcn_readlane(__float_as_uint(v), l));
}
__device__ __forceinline__ void unpack8(uint4 u, float (&f)[8]) {
  f[0] = __uint_as_float(u.x << 16); f[1] = __uint_as_float(u.x & 0xffff0000u);
  f[2] = __uint_as_float(u.y << 16); f[3] = __uint_as_float(u.y & 0xffff0000u);
  f[4] = __uint_as_float(u.z << 16); f[5] = __uint_as_float(u.z & 0xffff0000u);
  f[6] = __uint_as_float(u.w << 16); f[7] = __uint_as_float(u.w & 0xffff0000u);
}
__device__ __forceinline__ bf16x8 pack_bf8(float4 a, float4 b) {
  bf16x8 r;
  r[0] = (__bf16)a.x; r[1] = (__bf16)a.y; r[2] = (__bf16)a.z; r[3] = (__bf16)a.w;
  r[4] = (__bf16)b.x; r[5] = (__bf16)b.y; r[6] = (__bf16)b.z; r[7] = (__bf16)b.w;
  return r;
}

// ---------------- QKV via MFMA (+ deg/S zero prologue) ----------------
__global__ __launch_bounds__(256) void k_qkv_mfma(
    const float* __restrict__ x,
    const float* __restrict__ Wq, const float* __restrict__ bq,
    const float* __restrict__ Wk, const float* __restrict__ bk,
    const float* __restrict__ Wv, const float* __restrict__ bv,
    ushort* __restrict__ q, ushort* __restrict__ k, ushort* __restrict__ v,
    int* __restrict__ deg, float* __restrict__ S) {
  // fold the memsets into this first kernel (stream-ordered before k_hist)
  const int tid0 = blockIdx.x * 256 + threadIdx.x;
  if (tid0 < N_NODES) deg[tid0] = 0;
  if (tid0 < 16) S[tid0] = 0.f;

  const int lane = threadIdx.x & 63;
  const int wid  = threadIdx.x >> 6;
  const int r  = lane & 15;
  const int kg = lane >> 4;
  const float* Ws[3] = {Wq, Wk, Wv};
  const float* bs[3] = {bq, bk, bv};
  ushort* os[3] = {q, k, v};

  bf16x8 afrag[3][4][2];
  float  bias[3][4][4];
#pragma unroll
  for (int m = 0; m < 3; ++m)
#pragma unroll
    for (int nt = 0; nt < 4; ++nt) {
#pragma unroll
      for (int kk = 0; kk < 2; ++kk)
#pragma unroll
        for (int j = 0; j < 8; ++j)
          afrag[m][nt][kk][j] = (__bf16)Ws[m][(kk * 32 + kg * 8 + j) * 64 + nt * 16 + r];
#pragma unroll
      for (int j = 0; j < 4; ++j) bias[m][nt][j] = bs[m][nt * 16 + kg * 4 + j];
    }

  const int ntile = N_NODES / 16;  // 3125
  const int nw = gridDim.x * 4;
  for (int t = blockIdx.x * 4 + wid; t < ntile; t += nw) {
    const int base = t * 16;
    const float4* xr = reinterpret_cast<const float4*>(x + (size_t)(base + r) * 64 + kg * 8);
    const bf16x8 xf0 = pack_bf8(xr[0], xr[1]);
    const bf16x8 xf1 = pack_bf8(xr[8], xr[9]);
#pragma unroll
    for (int m = 0; m < 3; ++m) {
#pragma unroll
      for (int nt = 0; nt < 4; ++nt) {
        f32x4 acc = {bias[m][nt][0], bias[m][nt][1], bias[m][nt][2], bias[m][nt][3]};
        acc = __builtin_amdgcn_mfma_f32_16x16x32_bf16(afrag[m][nt][0], xf0, acc, 0, 0, 0);
        acc = __builtin_amdgcn_mfma_f32_16x16x32_bf16(afrag[m][nt][1], xf1, acc, 0, 0, 0);
        ushort4 pk;
        pk.x = f2bf(acc[0]); pk.y = f2bf(acc[1]); pk.z = f2bf(acc[2]); pk.w = f2bf(acc[3]);
        *reinterpret_cast<ushort4*>(os[m] + (size_t)(base + r) * 64 + nt * 16 + kg * 4) = pk;
      }
    }
  }
}

// ---------------- CSR build ----------------
__global__ __launch_bounds__(256) void k_hist(const int* __restrict__ edst,
                                              int* __restrict__ deg) {
  const int i = blockIdx.x * 256 + threadIdx.x;
  if (i < N_EDGES) atomicAdd(&deg[edst[i]], 1);
}

// single-block scan over 50k (R3-proven; ~3 us, replaces 3 dispatches)
__global__ __launch_bounds__(1024) void k_scan(const int* __restrict__ deg,
                                               int* __restrict__ rowptr,
                                               int* __restrict__ woff) {
  __shared__ int lsum[1024];
  const int tid = threadIdx.x;
  const int CH = 49;  // 1024*49 >= 50000
  const int base = tid * CH;
  int s = 0;
  for (int i = 0; i < CH; ++i) {
    const int idx = base + i;
    if (idx < N_NODES) s += deg[idx];
  }
  lsum[tid] = s;
  __syncthreads();
  for (int off = 1; off < 1024; off <<= 1) {
    const int t = (tid >= off) ? lsum[tid - off] : 0;
    __syncthreads();
    lsum[tid] += t;
    __syncthreads();
  }
  int ex = (tid == 0) ? 0 : lsum[tid - 1];
  for (int i = 0; i < CH; ++i) {
    const int idx = base + i;
    if (idx < N_NODES) {
      rowptr[idx] = ex;
      woff[idx] = ex;
      ex += deg[idx];
    }
  }
  if (tid == 1023) rowptr[N_NODES] = ex;
}

__global__ __launch_bounds__(256) void k_scatter(const int* __restrict__ esrc,
                                                 const int* __restrict__ edst,
                                                 int* __restrict__ woff,
                                                 int* __restrict__ srcp,
                                                 int* __restrict__ eidp) {
  const int i = blockIdx.x * 256 + threadIdx.x;
  if (i < N_EDGES) {
    const int pos = atomicAdd(&woff[edst[i]], 1);
    srcp[pos] = esrc[i];
    eidp[pos] = i;
  }
}

// ---------------- ee GEMM via MFMA -> fp8 e4m3, dst-sorted sequential ----------------
__global__ __launch_bounds__(256) void k_ee_mfma(
    const int* __restrict__ eidp, const float* __restrict__ ea,
    const float* __restrict__ We, const float* __restrict__ be,
    unsigned char* __restrict__ ee8) {
  const int lane = threadIdx.x & 63;
  const int wid  = threadIdx.x >> 6;
  const int r  = lane & 15;
  const int kg = lane >> 4;

  bf16x8 afrag[4];
  float  bias[4][4];
#pragma unroll
  for (int nt = 0; nt < 4; ++nt) {
#pragma unroll
    for (int j = 0; j < 8; ++j)
      afrag[nt][j] = (__bf16)We[(kg * 8 + j) * 64 + nt * 16 + r];
#pragma unroll
    for (int j = 0; j < 4; ++j) bias[nt][j] = be[nt * 16 + kg * 4 + j];
  }

  const int ntile = N_EDGES / 16;  // 50000
  const int nw = gridDim.x * 4;
  for (int t = blockIdx.x * 4 + wid; t < ntile; t += nw) {
    const int base = t * 16;
    const int eid = eidp[base + r];
    const float4* ar = reinterpret_cast<const float4*>(ea + (size_t)eid * 32 + kg * 8);
    const bf16x8 bfrag = pack_bf8(ar[0], ar[1]);
#pragma unroll
    for (int nt = 0; nt < 4; ++nt) {
      f32x4 acc = {bias[nt][0], bias[nt][1], bias[nt][2], bias[nt][3]};
      acc = __builtin_amdgcn_mfma_f32_16x16x32_bf16(afrag[nt], bfrag, acc, 0, 0, 0);
      uint rr = (uint)__builtin_amdgcn_cvt_pk_fp8_f32(acc[0], acc[1], 0, false);
      rr = (uint)__builtin_amdgcn_cvt_pk_fp8_f32(acc[2], acc[3], (int)rr, true);
      *reinterpret_cast<uint*>(ee8 + (size_t)(base + r) * 64 + nt * 16 + kg * 4) = rr;
    }
  }
}

// ---------------- gather: wave per node, lane=(edge-slot, head), fp8 ee stream ----------------
__global__ __launch_bounds__(256) void k_gather(
    const int* __restrict__ rowptr, const int* __restrict__ srcp,
    const unsigned char* __restrict__ ee8,
    const ushort* __restrict__ qb, const ushort* __restrict__ kb,
    const ushort* __restrict__ vb, const float* __restrict__ be,
    ushort* __restrict__ osum, float* __restrict__ S) {
  const int lane = threadIdx.x & 63;
  const int wid  = threadIdx.x >> 6;
  const int h = lane & 7, ei = lane >> 3;
  float bes[8];
#pragma unroll
  for (int i = 0; i < 8; ++i) bes[i] = be[h * 8 + i];
  float sacc = 0.f;
  const int nw = gridDim.x * 4;
  for (int n = blockIdx.x * 4 + wid; n < N_NODES; n += nw) {
    const int beg = rowptr[n], end = rowptr[n + 1];
    float qv[8];
    unpack8(*reinterpret_cast<const uint4*>(qb + (size_t)n * 64 + h * 8), qv);
    float macc[8];
#pragma unroll
    for (int i = 0; i < 8; ++i) macc[i] = 0.f;
    if (ei == 0) {  // self loop: ea=0 -> ee=be
      float kv[8], vv[8];
      unpack8(*reinterpret_cast<const uint4*>(kb + (size_t)n * 64 + h * 8), kv);
      unpack8(*reinterpret_cast<const uint4*>(vb + (size_t)n * 64 + h * 8), vv);
      float sc = 0.f;
#pragma unroll
      for (int i = 0; i < 8; ++i) sc = fmaf(qv[i], kv[i] + bes[i], sc);
      const float w = __expf(sc * 0.3535533905932738f);
      sacc += w;
#pragma unroll
      for (int i = 0; i < 8; ++i) macc[i] = w * (vv[i] + bes[i]);
    }
    int p = beg + ei;
    int src = (p < end) ? srcp[p] : 0;
    for (; p < end; p += 8) {
      const int nsrc = (p + 8 < end) ? srcp[p + 8] : 0;
      float ev[8], kv[8], vv[8];
      const uint2 er8 = *reinterpret_cast<const uint2*>(ee8 + (size_t)p * 64 + h * 8);
      ev[0] = __builtin_amdgcn_cvt_f32_fp8((int)er8.x, 0);
      ev[1] = __builtin_amdgcn_cvt_f32_fp8((int)er8.x, 1);
      ev[2] = __builtin_amdgcn_cvt_f32_fp8((int)er8.x, 2);
      ev[3] = __builtin_amdgcn_cvt_f32_fp8((int)er8.x, 3);
      ev[4] = __builtin_amdgcn_cvt_f32_fp8((int)er8.y, 0);
      ev[5] = __builtin_amdgcn_cvt_f32_fp8((int)er8.y, 1);
      ev[6] = __builtin_amdgcn_cvt_f32_fp8((int)er8.y, 2);
      ev[7] = __builtin_amdgcn_cvt_f32_fp8((int)er8.y, 3);
      unpack8(*reinterpret_cast<const uint4*>(kb + (size_t)src * 64 + h * 8), kv);
      unpack8(*reinterpret_cast<const uint4*>(vb + (size_t)src * 64 + h * 8), vv);
      float sc = 0.f;
#pragma unroll
      for (int i = 0; i < 8; ++i) sc = fmaf(qv[i], kv[i] + ev[i], sc);
      const float w = __expf(sc * 0.3535533905932738f);
      sacc += w;
#pragma unroll
      for (int i = 0; i < 8; ++i) macc[i] = fmaf(w, vv[i] + ev[i], macc[i]);
      src = nsrc;
    }
#pragma unroll
    for (int i = 0; i < 8; ++i) {
      macc[i] += __shfl_xor(macc[i], 8);
      macc[i] += __shfl_xor(macc[i], 16);
      macc[i] += __shfl_xor(macc[i], 32);
    }
    if (ei == 0) {
      uint pk[4];
#pragma unroll
      for (int i = 0; i < 4; ++i)
        pk[i] = (uint)f2bf(macc[2 * i]) | ((uint)f2bf(macc[2 * i + 1]) << 16);
      *reinterpret_cast<uint4*>(osum + (size_t)n * 64 + h * 8) =
          make_uint4(pk[0], pk[1], pk[2], pk[3]);
    }
  }
  sacc += __shfl_xor(sacc, 8);
  sacc += __shfl_xor(sacc, 16);
  sacc += __shfl_xor(sacc, 32);
  if (ei == 0) atomicAdd(&S[h], sacc);
}

// ---------------- LN1: (osum scaled) @ Wo + bo, +x, LN -> h ----------------
__global__ __launch_bounds__(256) void k_ln1_rl(
    const ushort* __restrict__ osum, const int* __restrict__ rowptr,
    const float* __restrict__ S, const float* __restrict__ x,
    const float* __restrict__ Wo, const float* __restrict__ bo,
    const float* __restrict__ g1, const float* __restrict__ b1,
    float* __restrict__ h) {
  const int lane = threadIdx.x & 63;
  const int wid  = threadIdx.x >> 6;
  float wcol[64];
#pragma unroll
  for (int j = 0; j < 64; ++j) wcol[j] = Wo[j * 64 + lane];
  const float bl = bo[lane];
  const float gl = g1[lane], b1l = b1[lane];
  const float invS = 1.0f / S[lane >> 3];
  const int nw = gridDim.x * 4;
  for (int n = blockIdx.x * 4 + wid; n < N_NODES; n += nw) {
    const float invc = 1.0f / (float)(rowptr[n + 1] - rowptr[n] + 1);
    const float val =
        __uint_as_float(((uint)osum[(size_t)n * 64 + lane]) << 16) * invS * invc;
    float acc = bl;
#pragma unroll
    for (int j = 0; j < 64; ++j) acc = fmaf(rlane(val, j), wcol[j], acc);
    const float t = x[(size_t)n * 64 + lane] + acc;
    float s = t;
    s += __shfl_xor(s, 1);  s += __shfl_xor(s, 2);  s += __shfl_xor(s, 4);
    s += __shfl_xor(s, 8);  s += __shfl_xor(s, 16); s += __shfl_xor(s, 32);
    const float m = s * (1.0f / 64.0f);
    const float d = t - m;
    float vs = d * d;
    vs += __shfl_xor(vs, 1);  vs += __shfl_xor(vs, 2);  vs += __shfl_xor(vs, 4);
    vs += __shfl_xor(vs, 8);  vs += __shfl_xor(vs, 16); vs += __shfl_xor(vs, 32);
    const float r = rsqrtf(vs * (1.0f / 64.0f) + 1e-5f);
    h[(size_t)n * 64 + lane] = d * r * gl + b1l;
  }
}

// ---------------- FFN1: f1 = gelu(h @ Wf1 + bf1), feature-half per blockIdx.y ----------------
__global__ __launch_bounds__(256) void k_ffn1_rl(
    const float* __restrict__ h, const float* __restrict__ Wf1,
    const float* __restrict__ bf1, float* __restrict__ f1) {
  const int lane = threadIdx.x & 63;
  const int wid  = threadIdx.x >> 6;
  const int f = blockIdx.y * 64 + lane;
  float wcol[64];
#pragma unroll
  for (int j = 0; j < 64; ++j) wcol[j] = Wf1[j * 128 + f];
  const float bl = bf1[f];
  const int nw = gridDim.x * 4;
  for (int n = blockIdx.x * 4 + wid; n < N_NODES; n += nw) {
    const float hr = h[(size_t)n * 64 + lane];
    float acc = bl;
#pragma unroll
    for (int j = 0; j < 64; ++j) acc = fmaf(rlane(hr, j), wcol[j], acc);
    f1[(size_t)n * 128 + f] = 0.5f * acc * (1.0f + erff(acc * 0.7071067811865475f));
  }
}

// ---------------- FFN2 + residual + LN2 -> out ----------------
__global__ __launch_bounds__(256) void k_ffn2_rl(
    const float* __restrict__ f1, const float* __restrict__ h,
    const float* __restrict__ Wf2, const float* __restrict__ bf2,
    const float* __restrict__ g2, const float* __restrict__ b2,
    float* __restrict__ out) {
  const int lane = threadIdx.x & 63;
  const int wid  = threadIdx.x >> 6;
  float wcol[128];
#pragma unroll
  for (int j = 0; j < 128; ++j) wcol[j] = Wf2[j * 64 + lane];
  const float bl = bf2[lane];
  const float gl = g2[lane], b2l = b2[lane];
  const int nw = gridDim.x * 4;
  for (int n = blockIdx.x * 4 + wid; n < N_NODES; n += nw) {
    const float a0 = f1[(size_t)n * 128 + lane];
    const float a1 = f1[(size_t)n * 128 + 64 + lane];
    float acc = bl;
#pragma unroll
    for (int j = 0; j < 64; ++j) acc = fmaf(rlane(a0, j), wcol[j], acc);
#pragma unroll
    for (int j = 0; j < 64; ++j) acc = fmaf(rlane(a1, j), wcol[64 + j], acc);
    const float t = h[(size_t)n * 64 + lane] + acc;
    float s = t;
    s += __shfl_xor(s, 1);  s += __shfl_xor(s, 2);  s += __shfl_xor(s, 4);
    s += __shfl_xor(s, 8);  s += __shfl_xor(s, 16); s += __shfl_xor(s, 32);
    const float m = s * (1.0f / 64.0f);
    const float d = t - m;
    float vs = d * d;
    vs += __shfl_xor(vs, 1);  vs += __shfl_xor(vs, 2);  vs += __shfl_xor(vs, 4);
    vs += __shfl_xor(vs, 8);  vs += __shfl_xor(vs, 16); vs += __shfl_xor(vs, 32);
    const float r = rsqrtf(vs * (1.0f / 64.0f) + 1e-5f);
    out[(size_t)n * 64 + lane] = d * r * gl + b2l;
  }
}

extern "C" void kernel_launch(void* const* d_in, const int* in_sizes, int n_in,
                              void* d_out, int out_size, void* d_ws, size_t ws_size,
                              hipStream_t stream) {
  const float* x    = (const float*)d_in[0];
  const int*   ei   = (const int*)d_in[1];
  const int*   esrc = ei;
  const int*   edst = ei + N_EDGES;
  const float* ea   = (const float*)d_in[2];
  const float* Wq   = (const float*)d_in[3];
  const float* bq   = (const float*)d_in[4];
  const float* Wk   = (const float*)d_in[5];
  const float* bk   = (const float*)d_in[6];
  const float* Wv   = (const float*)d_in[7];
  const float* bv   = (const float*)d_in[8];
  const float* We   = (const float*)d_in[9];
  const float* be   = (const float*)d_in[10];
  const float* Wo   = (const float*)d_in[11];
  const float* bo   = (const float*)d_in[12];
  const float* g1   = (const float*)d_in[13];
  const float* b1   = (const float*)d_in[14];
  const float* g2   = (const float*)d_in[15];
  const float* b2   = (const float*)d_in[16];
  const float* Wf1  = (const float*)d_in[17];
  const float* bf1  = (const float*)d_in[18];
  const float* Wf2  = (const float*)d_in[19];
  const float* bf2  = (const float*)d_in[20];

  float* ws    = (float*)d_ws;
  ushort* q    = (ushort*)(ws + Q_OFF);
  ushort* k    = (ushort*)(ws + K_OFF);
  ushort* v    = (ushort*)(ws + V_OFF);
  unsigned char* ee8 = (unsigned char*)(ws + EE_OFF);
  ushort* osum = (ushort*)(ws + OS_OFF);
  float* S     = ws + S_OFF;
  int*   rowptr = (int*)(ws + RP_OFF);
  int*   srcp   = (int*)(ws + SRCP_OFF);
  int*   eidp   = (int*)(ws + EIDP_OFF);
  int*   deg    = (int*)(ws + DEG_OFF);
  int*   woff   = (int*)(ws + WOFF_OFF);
  float* h     = ws + H_OFF;
  float* f1    = ws + F1_OFF;
  float* out   = (float*)d_out;

  const dim3 B(256);
  const int edgeBlocks = (N_EDGES + 255) / 256;  // 3125

  k_qkv_mfma<<<dim3(256), B, 0, stream>>>(x, Wq, bq, Wk, bk, Wv, bv, q, k, v, deg, S);
  k_hist<<<dim3(edgeBlocks), B, 0, stream>>>(edst, deg);
  k_scan<<<dim3(1), dim3(1024), 0, stream>>>(deg, rowptr, woff);
  k_scatter<<<dim3(edgeBlocks), B, 0, stream>>>(esrc, edst, woff, srcp, eidp);
  k_ee_mfma<<<dim3(1024), B, 0, stream>>>(eidp, ea, We, be, ee8);
  k_gather<<<dim3(2048), B, 0, stream>>>(rowptr, srcp, ee8, q, k, v, be, osum, S);
  k_ln1_rl<<<dim3(256), B, 0, stream>>>(osum, rowptr, S, x, Wo, bo, g1, b1, h);
  k_ffn1_rl<<<dim3(256, 2), B, 0, stream>>>(h, Wf1, bf1, f1);
  k_ffn2_rl<<<dim3(256), B, 0, stream>>>(f1, h, Wf2, bf2, g2, b2, out);
}

// Round 10
// 262.465 us; speedup vs baseline: 2.0114x; 2.0114x over previous
//
#include <hip/hip_runtime.h>
#include <hip/hip_bf16.h>
#include <math.h>

#define N_NODES 50000
#define N_EDGES 800000
#define D 64
#define ED 32

// ws layout (float-slot offsets). Total ~20.95M slots = 83.8 MB.
#define Q_OFF    0          // bf16 q (1.6M slots)
#define K_OFF    1600000    // bf16 k
#define V_OFF    3200000    // bf16 v
#define EE_OFF   4800000    // fp8 ee, dst-sorted: 800k x 64 B = 12.8M slots
#define OS_OFF   17600000   // bf16 osum: 1.6M slots
#define S_OFF    19200000   // 16
#define RP_OFF   19200016   // 50,001 (+1 pad)
#define SRCP_OFF 19250018   // 800k ints
#define EIDP_OFF 20050018   // 800k ints
#define DEG_OFF  20850018   // 50k ints
#define WOFF_OFF 20900018   // 50k ints
#define BSUM_OFF 20950018   // 256 ints
// aliases (dead ranges reused):
#define H_OFF    0          // bf16 h (1.6M slots) over q (dead after gather)
#define F1_OFF   EE_OFF     // bf16 f1 (3.2M slots) over ee (dead after gather)

typedef __bf16 bf16x8 __attribute__((ext_vector_type(8)));
typedef float  f32x4  __attribute__((ext_vector_type(4)));

__device__ __forceinline__ ushort f2bf(float f) {
  uint u = __float_as_uint(f);
  uint r = (u + 0x7FFFu + ((u >> 16) & 1u)) >> 16;
  return (ushort)r;
}
__device__ __forceinline__ float bfu2f(ushort u) {
  return __uint_as_float(((uint)u) << 16);
}
__device__ __forceinline__ void unpack8(uint4 u, float (&f)[8]) {
  f[0] = __uint_as_float(u.x << 16); f[1] = __uint_as_float(u.x & 0xffff0000u);
  f[2] = __uint_as_float(u.y << 16); f[3] = __uint_as_float(u.y & 0xffff0000u);
  f[4] = __uint_as_float(u.z << 16); f[5] = __uint_as_float(u.z & 0xffff0000u);
  f[6] = __uint_as_float(u.w << 16); f[7] = __uint_as_float(u.w & 0xffff0000u);
}
__device__ __forceinline__ bf16x8 pack_bf8(float4 a, float4 b) {
  bf16x8 r;
  r[0] = (__bf16)a.x; r[1] = (__bf16)a.y; r[2] = (__bf16)a.z; r[3] = (__bf16)a.w;
  r[4] = (__bf16)b.x; r[5] = (__bf16)b.y; r[6] = (__bf16)b.z; r[7] = (__bf16)b.w;
  return r;
}

// ---------------- QKV via MFMA (+ deg/S zero prologue) ----------------
__global__ __launch_bounds__(256) void k_qkv_mfma(
    const float* __restrict__ x,
    const float* __restrict__ Wq, const float* __restrict__ bq,
    const float* __restrict__ Wk, const float* __restrict__ bk,
    const float* __restrict__ Wv, const float* __restrict__ bv,
    ushort* __restrict__ q, ushort* __restrict__ k, ushort* __restrict__ v,
    int* __restrict__ deg, float* __restrict__ S) {
  const int tid0 = blockIdx.x * 256 + threadIdx.x;
  if (tid0 < N_NODES) deg[tid0] = 0;
  if (tid0 < 16) S[tid0] = 0.f;

  const int lane = threadIdx.x & 63;
  const int wid  = threadIdx.x >> 6;
  const int r  = lane & 15;
  const int kg = lane >> 4;
  const float* Ws[3] = {Wq, Wk, Wv};
  const float* bs[3] = {bq, bk, bv};
  ushort* os[3] = {q, k, v};

  bf16x8 afrag[3][4][2];
  float  bias[3][4][4];
#pragma unroll
  for (int m = 0; m < 3; ++m)
#pragma unroll
    for (int nt = 0; nt < 4; ++nt) {
#pragma unroll
      for (int kk = 0; kk < 2; ++kk)
#pragma unroll
        for (int j = 0; j < 8; ++j)
          afrag[m][nt][kk][j] = (__bf16)Ws[m][(kk * 32 + kg * 8 + j) * 64 + nt * 16 + r];
#pragma unroll
      for (int j = 0; j < 4; ++j) bias[m][nt][j] = bs[m][nt * 16 + kg * 4 + j];
    }

  const int ntile = N_NODES / 16;  // 3125
  const int nw = gridDim.x * 4;
  for (int t = blockIdx.x * 4 + wid; t < ntile; t += nw) {
    const int base = t * 16;
    const float4* xr = reinterpret_cast<const float4*>(x + (size_t)(base + r) * 64 + kg * 8);
    const bf16x8 xf0 = pack_bf8(xr[0], xr[1]);
    const bf16x8 xf1 = pack_bf8(xr[8], xr[9]);
#pragma unroll
    for (int m = 0; m < 3; ++m) {
#pragma unroll
      for (int nt = 0; nt < 4; ++nt) {
        f32x4 acc = {bias[m][nt][0], bias[m][nt][1], bias[m][nt][2], bias[m][nt][3]};
        acc = __builtin_amdgcn_mfma_f32_16x16x32_bf16(afrag[m][nt][0], xf0, acc, 0, 0, 0);
        acc = __builtin_amdgcn_mfma_f32_16x16x32_bf16(afrag[m][nt][1], xf1, acc, 0, 0, 0);
        ushort4 pk;
        pk.x = f2bf(acc[0]); pk.y = f2bf(acc[1]); pk.z = f2bf(acc[2]); pk.w = f2bf(acc[3]);
        *reinterpret_cast<ushort4*>(os[m] + (size_t)(base + r) * 64 + nt * 16 + kg * 4) = pk;
      }
    }
  }
}

// ---------------- CSR build ----------------
__global__ __launch_bounds__(256) void k_hist(const int* __restrict__ edst,
                                              int* __restrict__ deg) {
  const int i = blockIdx.x * 256 + threadIdx.x;
  if (i < N_EDGES) atomicAdd(&deg[edst[i]], 1);
}

__global__ __launch_bounds__(256) void k_scan_a(const int* __restrict__ deg,
                                                int* __restrict__ bsum) {
  __shared__ int lds[256];
  const int i = blockIdx.x * 256 + threadIdx.x;
  lds[threadIdx.x] = (i < N_NODES) ? deg[i] : 0;
  __syncthreads();
  for (int s = 128; s > 0; s >>= 1) {
    if (threadIdx.x < s) lds[threadIdx.x] += lds[threadIdx.x + s];
    __syncthreads();
  }
  if (threadIdx.x == 0) bsum[blockIdx.x] = lds[0];
}

__global__ __launch_bounds__(256) void k_scan_b(int* __restrict__ bsum, int nb) {
  __shared__ int lds[256];
  const int t = threadIdx.x;
  const int d = (t < nb) ? bsum[t] : 0;
  lds[t] = d;
  __syncthreads();
  for (int off = 1; off < 256; off <<= 1) {
    const int val = (t >= off) ? lds[t - off] : 0;
    __syncthreads();
    lds[t] += val;
    __syncthreads();
  }
  if (t < nb) bsum[t] = lds[t] - d;  // exclusive
}

__global__ __launch_bounds__(256) void k_scan_c(const int* __restrict__ deg,
                                                const int* __restrict__ bsum,
                                                int* __restrict__ rowptr,
                                                int* __restrict__ woff) {
  __shared__ int lds[256];
  const int i = blockIdx.x * 256 + threadIdx.x;
  const int d = (i < N_NODES) ? deg[i] : 0;
  lds[threadIdx.x] = d;
  __syncthreads();
  for (int off = 1; off < 256; off <<= 1) {
    const int val = (threadIdx.x >= off) ? lds[threadIdx.x - off] : 0;
    __syncthreads();
    lds[threadIdx.x] += val;
    __syncthreads();
  }
  const int ex = bsum[blockIdx.x] + lds[threadIdx.x] - d;
  if (i < N_NODES) { rowptr[i] = ex; woff[i] = ex; }
  if (i == N_NODES - 1) rowptr[N_NODES] = ex + d;
}

__global__ __launch_bounds__(256) void k_scatter(const int* __restrict__ esrc,
                                                 const int* __restrict__ edst,
                                                 int* __restrict__ woff,
                                                 int* __restrict__ srcp,
                                                 int* __restrict__ eidp) {
  const int i = blockIdx.x * 256 + threadIdx.x;
  if (i < N_EDGES) {
    const int pos = atomicAdd(&woff[edst[i]], 1);
    srcp[pos] = esrc[i];
    eidp[pos] = i;
  }
}

// ---------------- ee GEMM via MFMA -> fp8 e4m3, dst-sorted sequential ----------------
__global__ __launch_bounds__(256) void k_ee_mfma(
    const int* __restrict__ eidp, const float* __restrict__ ea,
    const float* __restrict__ We, const float* __restrict__ be,
    unsigned char* __restrict__ ee8) {
  const int lane = threadIdx.x & 63;
  const int wid  = threadIdx.x >> 6;
  const int r  = lane & 15;
  const int kg = lane >> 4;

  bf16x8 afrag[4];
  float  bias[4][4];
#pragma unroll
  for (int nt = 0; nt < 4; ++nt) {
#pragma unroll
    for (int j = 0; j < 8; ++j)
      afrag[nt][j] = (__bf16)We[(kg * 8 + j) * 64 + nt * 16 + r];
#pragma unroll
    for (int j = 0; j < 4; ++j) bias[nt][j] = be[nt * 16 + kg * 4 + j];
  }

  const int ntile = N_EDGES / 16;  // 50000
  const int nw = gridDim.x * 4;
  for (int t = blockIdx.x * 4 + wid; t < ntile; t += nw) {
    const int base = t * 16;
    const int eid = eidp[base + r];
    const float4* ar = reinterpret_cast<const float4*>(ea + (size_t)eid * 32 + kg * 8);
    const bf16x8 bfrag = pack_bf8(ar[0], ar[1]);
#pragma unroll
    for (int nt = 0; nt < 4; ++nt) {
      f32x4 acc = {bias[nt][0], bias[nt][1], bias[nt][2], bias[nt][3]};
      acc = __builtin_amdgcn_mfma_f32_16x16x32_bf16(afrag[nt], bfrag, acc, 0, 0, 0);
      uint rr = (uint)__builtin_amdgcn_cvt_pk_fp8_f32(acc[0], acc[1], 0, false);
      rr = (uint)__builtin_amdgcn_cvt_pk_fp8_f32(acc[2], acc[3], (int)rr, true);
      *reinterpret_cast<uint*>(ee8 + (size_t)(base + r) * 64 + nt * 16 + kg * 4) = rr;
    }
  }
}

// ---------------- gather: wave per node, lane=(edge-slot, head), fp8 ee stream ----------------
__global__ __launch_bounds__(256) void k_gather(
    const int* __restrict__ rowptr, const int* __restrict__ srcp,
    const unsigned char* __restrict__ ee8,
    const ushort* __restrict__ qb, const ushort* __restrict__ kb,
    const ushort* __restrict__ vb, const float* __restrict__ be,
    ushort* __restrict__ osum, float* __restrict__ S) {
  const int lane = threadIdx.x & 63;
  const int wid  = threadIdx.x >> 6;
  const int h = lane & 7, ei = lane >> 3;
  float bes[8];
#pragma unroll
  for (int i = 0; i < 8; ++i) bes[i] = be[h * 8 + i];
  float sacc = 0.f;
  const int nw = gridDim.x * 4;
  for (int n = blockIdx.x * 4 + wid; n < N_NODES; n += nw) {
    const int beg = rowptr[n], end = rowptr[n + 1];
    float qv[8];
    unpack8(*reinterpret_cast<const uint4*>(qb + (size_t)n * 64 + h * 8), qv);
    float macc[8];
#pragma unroll
    for (int i = 0; i < 8; ++i) macc[i] = 0.f;
    if (ei == 0) {  // self loop: ea=0 -> ee=be
      float kv[8], vv[8];
      unpack8(*reinterpret_cast<const uint4*>(kb + (size_t)n * 64 + h * 8), kv);
      unpack8(*reinterpret_cast<const uint4*>(vb + (size_t)n * 64 + h * 8), vv);
      float sc = 0.f;
#pragma unroll
      for (int i = 0; i < 8; ++i) sc = fmaf(qv[i], kv[i] + bes[i], sc);
      const float w = __expf(sc * 0.3535533905932738f);
      sacc += w;
#pragma unroll
      for (int i = 0; i < 8; ++i) macc[i] = w * (vv[i] + bes[i]);
    }
    int p = beg + ei;
    int src = (p < end) ? srcp[p] : 0;
    for (; p < end; p += 8) {
      const int nsrc = (p + 8 < end) ? srcp[p + 8] : 0;
      float ev[8], kv[8], vv[8];
      const uint2 er8 = *reinterpret_cast<const uint2*>(ee8 + (size_t)p * 64 + h * 8);
      ev[0] = __builtin_amdgcn_cvt_f32_fp8((int)er8.x, 0);
      ev[1] = __builtin_amdgcn_cvt_f32_fp8((int)er8.x, 1);
      ev[2] = __builtin_amdgcn_cvt_f32_fp8((int)er8.x, 2);
      ev[3] = __builtin_amdgcn_cvt_f32_fp8((int)er8.x, 3);
      ev[4] = __builtin_amdgcn_cvt_f32_fp8((int)er8.y, 0);
      ev[5] = __builtin_amdgcn_cvt_f32_fp8((int)er8.y, 1);
      ev[6] = __builtin_amdgcn_cvt_f32_fp8((int)er8.y, 2);
      ev[7] = __builtin_amdgcn_cvt_f32_fp8((int)er8.y, 3);
      unpack8(*reinterpret_cast<const uint4*>(kb + (size_t)src * 64 + h * 8), kv);
      unpack8(*reinterpret_cast<const uint4*>(vb + (size_t)src * 64 + h * 8), vv);
      float sc = 0.f;
#pragma unroll
      for (int i = 0; i < 8; ++i) sc = fmaf(qv[i], kv[i] + ev[i], sc);
      const float w = __expf(sc * 0.3535533905932738f);
      sacc += w;
#pragma unroll
      for (int i = 0; i < 8; ++i) macc[i] = fmaf(w, vv[i] + ev[i], macc[i]);
      src = nsrc;
    }
#pragma unroll
    for (int i = 0; i < 8; ++i) {
      macc[i] += __shfl_xor(macc[i], 8);
      macc[i] += __shfl_xor(macc[i], 16);
      macc[i] += __shfl_xor(macc[i], 32);
    }
    if (ei == 0) {
      uint pk[4];
#pragma unroll
      for (int i = 0; i < 4; ++i)
        pk[i] = (uint)f2bf(macc[2 * i]) | ((uint)f2bf(macc[2 * i + 1]) << 16);
      *reinterpret_cast<uint4*>(osum + (size_t)n * 64 + h * 8) =
          make_uint4(pk[0], pk[1], pk[2], pk[3]);
    }
  }
  sacc += __shfl_xor(sacc, 8);
  sacc += __shfl_xor(sacc, 16);
  sacc += __shfl_xor(sacc, 32);
  if (ei == 0) atomicAdd(&S[h], sacc);
}

// ---------------- LN1 via MFMA: h = LN(x + (osum/(S*cnt)) @ Wo + bo) -> bf16 ----------------
__global__ __launch_bounds__(256) void k_ln1_mfma(
    const ushort* __restrict__ osum, const int* __restrict__ rowptr,
    const float* __restrict__ S, const float* __restrict__ x,
    const float* __restrict__ Wo, const float* __restrict__ bo,
    const float* __restrict__ g1, const float* __restrict__ b1,
    ushort* __restrict__ h) {
  const int lane = threadIdx.x & 63;
  const int wid  = threadIdx.x >> 6;
  const int r  = lane & 15;
  const int kg = lane >> 4;

  bf16x8 afrag[4][2];
  float bias[4][4], g1f[4][4], b1f[4][4];
#pragma unroll
  for (int nt = 0; nt < 4; ++nt) {
#pragma unroll
    for (int kk = 0; kk < 2; ++kk)
#pragma unroll
      for (int j = 0; j < 8; ++j)
        afrag[nt][kk][j] = (__bf16)Wo[(kk * 32 + kg * 8 + j) * 64 + nt * 16 + r];
#pragma unroll
    for (int j = 0; j < 4; ++j) {
      bias[nt][j] = bo[nt * 16 + kg * 4 + j];
      g1f[nt][j]  = g1[nt * 16 + kg * 4 + j];
      b1f[nt][j]  = b1[nt * 16 + kg * 4 + j];
    }
  }
  float invSv[8];
#pragma unroll
  for (int i = 0; i < 8; ++i) invSv[i] = 1.0f / S[i];

  const int ntile = N_NODES / 16;  // 3125
  const int nw = gridDim.x * 4;
  for (int t = blockIdx.x * 4 + wid; t < ntile; t += nw) {
    const int node = t * 16 + r;
    const float invc = 1.0f / (float)(rowptr[node + 1] - rowptr[node] + 1);
    bf16x8 bfrag[2];
#pragma unroll
    for (int kk = 0; kk < 2; ++kk) {
      float tmp[8];
      unpack8(*reinterpret_cast<const uint4*>(osum + (size_t)node * 64 + kk * 32 + kg * 8), tmp);
      const float sc = invSv[kk * 4 + kg] * invc;
      bf16x8 bf;
#pragma unroll
      for (int e = 0; e < 8; ++e) bf[e] = (__bf16)(tmp[e] * sc);
      bfrag[kk] = bf;
    }
    float tv[4][4];
    float sum = 0.f;
#pragma unroll
    for (int nt = 0; nt < 4; ++nt) {
      f32x4 acc = {bias[nt][0], bias[nt][1], bias[nt][2], bias[nt][3]};
      acc = __builtin_amdgcn_mfma_f32_16x16x32_bf16(afrag[nt][0], bfrag[0], acc, 0, 0, 0);
      acc = __builtin_amdgcn_mfma_f32_16x16x32_bf16(afrag[nt][1], bfrag[1], acc, 0, 0, 0);
      const float4 xv = *reinterpret_cast<const float4*>(x + (size_t)node * 64 + nt * 16 + kg * 4);
      tv[nt][0] = acc[0] + xv.x; tv[nt][1] = acc[1] + xv.y;
      tv[nt][2] = acc[2] + xv.z; tv[nt][3] = acc[3] + xv.w;
      sum += (tv[nt][0] + tv[nt][1]) + (tv[nt][2] + tv[nt][3]);
    }
    sum += __shfl_xor(sum, 16);
    sum += __shfl_xor(sum, 32);
    const float m = sum * (1.0f / 64.0f);
    float var = 0.f;
#pragma unroll
    for (int nt = 0; nt < 4; ++nt)
#pragma unroll
      for (int j = 0; j < 4; ++j) { const float d = tv[nt][j] - m; var = fmaf(d, d, var); }
    var += __shfl_xor(var, 16);
    var += __shfl_xor(var, 32);
    const float rinv = rsqrtf(var * (1.0f / 64.0f) + 1e-5f);
#pragma unroll
    for (int nt = 0; nt < 4; ++nt) {
      ushort4 pk;
      pk.x = f2bf((tv[nt][0] - m) * rinv * g1f[nt][0] + b1f[nt][0]);
      pk.y = f2bf((tv[nt][1] - m) * rinv * g1f[nt][1] + b1f[nt][1]);
      pk.z = f2bf((tv[nt][2] - m) * rinv * g1f[nt][2] + b1f[nt][2]);
      pk.w = f2bf((tv[nt][3] - m) * rinv * g1f[nt][3] + b1f[nt][3]);
      *reinterpret_cast<ushort4*>(h + (size_t)node * 64 + nt * 16 + kg * 4) = pk;
    }
  }
}

// ---------------- FFN1 via MFMA: f1 = gelu(h @ Wf1 + bf1) -> bf16 ----------------
__global__ __launch_bounds__(256) void k_ffn1_mfma(
    const ushort* __restrict__ h, const float* __restrict__ Wf1,
    const float* __restrict__ bf1, ushort* __restrict__ f1) {
  const int lane = threadIdx.x & 63;
  const int wid  = threadIdx.x >> 6;
  const int r  = lane & 15;
  const int kg = lane >> 4;

  bf16x8 afrag[8][2];
  float bias[8][4];
#pragma unroll
  for (int nt = 0; nt < 8; ++nt) {
#pragma unroll
    for (int kk = 0; kk < 2; ++kk)
#pragma unroll
      for (int j = 0; j < 8; ++j)
        afrag[nt][kk][j] = (__bf16)Wf1[(kk * 32 + kg * 8 + j) * 128 + nt * 16 + r];
#pragma unroll
    for (int j = 0; j < 4; ++j) bias[nt][j] = bf1[nt * 16 + kg * 4 + j];
  }

  const int ntile = N_NODES / 16;  // 3125
  const int nw = gridDim.x * 4;
  for (int t = blockIdx.x * 4 + wid; t < ntile; t += nw) {
    const int node = t * 16 + r;
    const bf16x8 bf0 = *reinterpret_cast<const bf16x8*>(h + (size_t)node * 64 + kg * 8);
    const bf16x8 bf1g = *reinterpret_cast<const bf16x8*>(h + (size_t)node * 64 + 32 + kg * 8);
#pragma unroll
    for (int nt = 0; nt < 8; ++nt) {
      f32x4 acc = {bias[nt][0], bias[nt][1], bias[nt][2], bias[nt][3]};
      acc = __builtin_amdgcn_mfma_f32_16x16x32_bf16(afrag[nt][0], bf0, acc, 0, 0, 0);
      acc = __builtin_amdgcn_mfma_f32_16x16x32_bf16(afrag[nt][1], bf1g, acc, 0, 0, 0);
      ushort4 pk;
      pk.x = f2bf(0.5f * acc[0] * (1.0f + erff(acc[0] * 0.7071067811865475f)));
      pk.y = f2bf(0.5f * acc[1] * (1.0f + erff(acc[1] * 0.7071067811865475f)));
      pk.z = f2bf(0.5f * acc[2] * (1.0f + erff(acc[2] * 0.7071067811865475f)));
      pk.w = f2bf(0.5f * acc[3] * (1.0f + erff(acc[3] * 0.7071067811865475f)));
      *reinterpret_cast<ushort4*>(f1 + (size_t)node * 128 + nt * 16 + kg * 4) = pk;
    }
  }
}

// ---------------- FFN2 via MFMA + residual + LN2 -> out (f32) ----------------
__global__ __launch_bounds__(256) void k_ffn2_mfma(
    const ushort* __restrict__ f1, const ushort* __restrict__ h,
    const float* __restrict__ Wf2, const float* __restrict__ bf2,
    const float* __restrict__ g2, const float* __restrict__ b2,
    float* __restrict__ out) {
  const int lane = threadIdx.x & 63;
  const int wid  = threadIdx.x >> 6;
  const int r  = lane & 15;
  const int kg = lane >> 4;

  bf16x8 afrag[4][4];
  float bias[4][4], g2f[4][4], b2f[4][4];
#pragma unroll
  for (int nt = 0; nt < 4; ++nt) {
#pragma unroll
    for (int kk = 0; kk < 4; ++kk)
#pragma unroll
      for (int j = 0; j < 8; ++j)
        afrag[nt][kk][j] = (__bf16)Wf2[(kk * 32 + kg * 8 + j) * 64 + nt * 16 + r];
#pragma unroll
    for (int j = 0; j < 4; ++j) {
      bias[nt][j] = bf2[nt * 16 + kg * 4 + j];
      g2f[nt][j]  = g2[nt * 16 + kg * 4 + j];
      b2f[nt][j]  = b2[nt * 16 + kg * 4 + j];
    }
  }

  const int ntile = N_NODES / 16;  // 3125
  const int nw = gridDim.x * 4;
  for (int t = blockIdx.x * 4 + wid; t < ntile; t += nw) {
    const int node = t * 16 + r;
    bf16x8 bfrag[4];
#pragma unroll
    for (int kk = 0; kk < 4; ++kk)
      bfrag[kk] = *reinterpret_cast<const bf16x8*>(f1 + (size_t)node * 128 + kk * 32 + kg * 8);
    float tv[4][4];
    float sum = 0.f;
#pragma unroll
    for (int nt = 0; nt < 4; ++nt) {
      f32x4 acc = {bias[nt][0], bias[nt][1], bias[nt][2], bias[nt][3]};
      acc = __builtin_amdgcn_mfma_f32_16x16x32_bf16(afrag[nt][0], bfrag[0], acc, 0, 0, 0);
      acc = __builtin_amdgcn_mfma_f32_16x16x32_bf16(afrag[nt][1], bfrag[1], acc, 0, 0, 0);
      acc = __builtin_amdgcn_mfma_f32_16x16x32_bf16(afrag[nt][2], bfrag[2], acc, 0, 0, 0);
      acc = __builtin_amdgcn_mfma_f32_16x16x32_bf16(afrag[nt][3], bfrag[3], acc, 0, 0, 0);
      const ushort4 hv = *reinterpret_cast<const ushort4*>(h + (size_t)node * 64 + nt * 16 + kg * 4);
      tv[nt][0] = acc[0] + bfu2f(hv.x); tv[nt][1] = acc[1] + bfu2f(hv.y);
      tv[nt][2] = acc[2] + bfu2f(hv.z); tv[nt][3] = acc[3] + bfu2f(hv.w);
      sum += (tv[nt][0] + tv[nt][1]) + (tv[nt][2] + tv[nt][3]);
    }
    sum += __shfl_xor(sum, 16);
    sum += __shfl_xor(sum, 32);
    const float m = sum * (1.0f / 64.0f);
    float var = 0.f;
#pragma unroll
    for (int nt = 0; nt < 4; ++nt)
#pragma unroll
      for (int j = 0; j < 4; ++j) { const float d = tv[nt][j] - m; var = fmaf(d, d, var); }
    var += __shfl_xor(var, 16);
    var += __shfl_xor(var, 32);
    const float rinv = rsqrtf(var * (1.0f / 64.0f) + 1e-5f);
#pragma unroll
    for (int nt = 0; nt < 4; ++nt) {
      float4 o;
      o.x = (tv[nt][0] - m) * rinv * g2f[nt][0] + b2f[nt][0];
      o.y = (tv[nt][1] - m) * rinv * g2f[nt][1] + b2f[nt][1];
      o.z = (tv[nt][2] - m) * rinv * g2f[nt][2] + b2f[nt][2];
      o.w = (tv[nt][3] - m) * rinv * g2f[nt][3] + b2f[nt][3];
      *reinterpret_cast<float4*>(out + (size_t)node * 64 + nt * 16 + kg * 4) = o;
    }
  }
}

extern "C" void kernel_launch(void* const* d_in, const int* in_sizes, int n_in,
                              void* d_out, int out_size, void* d_ws, size_t ws_size,
                              hipStream_t stream) {
  const float* x    = (const float*)d_in[0];
  const int*   ei   = (const int*)d_in[1];
  const int*   esrc = ei;
  const int*   edst = ei + N_EDGES;
  const float* ea   = (const float*)d_in[2];
  const float* Wq   = (const float*)d_in[3];
  const float* bq   = (const float*)d_in[4];
  const float* Wk   = (const float*)d_in[5];
  const float* bk   = (const float*)d_in[6];
  const float* Wv   = (const float*)d_in[7];
  const float* bv   = (const float*)d_in[8];
  const float* We   = (const float*)d_in[9];
  const float* be   = (const float*)d_in[10];
  const float* Wo   = (const float*)d_in[11];
  const float* bo   = (const float*)d_in[12];
  const float* g1   = (const float*)d_in[13];
  const float* b1   = (const float*)d_in[14];
  const float* g2   = (const float*)d_in[15];
  const float* b2   = (const float*)d_in[16];
  const float* Wf1  = (const float*)d_in[17];
  const float* bf1  = (const float*)d_in[18];
  const float* Wf2  = (const float*)d_in[19];
  const float* bf2  = (const float*)d_in[20];

  float* ws    = (float*)d_ws;
  ushort* q    = (ushort*)(ws + Q_OFF);
  ushort* k    = (ushort*)(ws + K_OFF);
  ushort* v    = (ushort*)(ws + V_OFF);
  unsigned char* ee8 = (unsigned char*)(ws + EE_OFF);
  ushort* osum = (ushort*)(ws + OS_OFF);
  float* S     = ws + S_OFF;
  int*   rowptr = (int*)(ws + RP_OFF);
  int*   srcp   = (int*)(ws + SRCP_OFF);
  int*   eidp   = (int*)(ws + EIDP_OFF);
  int*   deg    = (int*)(ws + DEG_OFF);
  int*   woff   = (int*)(ws + WOFF_OFF);
  int*   bsum   = (int*)(ws + BSUM_OFF);
  ushort* h    = (ushort*)(ws + H_OFF);
  ushort* f1   = (ushort*)(ws + F1_OFF);
  float* out   = (float*)d_out;

  const dim3 B(256);
  const int nodeBlocks = (N_NODES + 255) / 256;  // 196
  const int edgeBlocks = (N_EDGES + 255) / 256;  // 3125

  k_qkv_mfma<<<dim3(256), B, 0, stream>>>(x, Wq, bq, Wk, bk, Wv, bv, q, k, v, deg, S);
  k_hist<<<dim3(edgeBlocks), B, 0, stream>>>(edst, deg);
  k_scan_a<<<dim3(nodeBlocks), B, 0, stream>>>(deg, bsum);
  k_scan_b<<<dim3(1), B, 0, stream>>>(bsum, nodeBlocks);
  k_scan_c<<<dim3(nodeBlocks), B, 0, stream>>>(deg, bsum, rowptr, woff);
  k_scatter<<<dim3(edgeBlocks), B, 0, stream>>>(esrc, edst, woff, srcp, eidp);
  k_ee_mfma<<<dim3(1024), B, 0, stream>>>(eidp, ea, We, be, ee8);
  k_gather<<<dim3(1024), B, 0, stream>>>(rowptr, srcp, ee8, q, k, v, be, osum, S);
  k_ln1_mfma<<<dim3(256), B, 0, stream>>>(osum, rowptr, S, x, Wo, bo, g1, b1, h);
  k_ffn1_mfma<<<dim3(256), B, 0, stream>>>(h, Wf1, bf1, f1);
  k_ffn2_mfma<<<dim3(256), B, 0, stream>>>(f1, h, Wf2, bf2, g2, b2, out);
}